// Round 11
// baseline (27.630 us; speedup 1.0000x reference)
//
#include <hip/hip_runtime.h>

// Problem constants (from reference setup_inputs)
constexpr int Bn = 16;
constexpr int Hn = 512;
constexpr int Wn = 512;
constexpr int PADR = 15;              // 31x31 window, pad 15
constexpr float INV_KK = 1.0f / (31.0f * 31.0f);
constexpr int NBLK = 1024;            // 64 row-groups x 16 batches

// XCD-aware flat-block decode: blocks with equal (fid%8) land on the same
// XCD (dispatch round-robins). Pin batches {2x,2x+1} to XCD x so the u8
// buffer (256 KB/batch) stays L2-resident. Bijective for grids 16*G.
__device__ __forceinline__ void decode_fid(int fid, int& b, int& grp) {
    b = (fid & 7) * 2 + ((fid >> 3) & 1);
    grp = fid >> 4;
}

// ---- pass A: pack mask + horizontal 31-tap box -> combined u8 ------------
// byte = hbox(m)[0..31] | (m << 7).
// flat grid 1024; 4 waves; wave owns 2 rows; lane owns 8 cols.
__global__ void pack_hbox_kernel(const int* __restrict__ mask,
                                 unsigned char* __restrict__ hm8) {
    int b, grp;
    decode_fid(blockIdx.x, b, grp);
    const int lane = threadIdx.x & 63;
    const int wv = threadIdx.x >> 6;
    const int c0 = lane * 8;

    const int* mb = mask + (size_t)b * Hn * Wn;
    unsigned char* h8 = hm8 + (size_t)b * Hn * Wn;

#pragma unroll
    for (int rr = 0; rr < 2; ++rr) {
        const int r = grp * 8 + wv * 2 + rr;
        const int4 a = *reinterpret_cast<const int4*>(mb + (size_t)r * Wn + c0);
        const int4 c = *reinterpret_cast<const int4*>(mb + (size_t)r * Wn + c0 + 4);
        const int mv[8] = {a.x, a.y, a.z, a.w, c.x, c.y, c.z, c.w};

        unsigned int w0 = 0, w1 = 0;                   // packed mask bytes
        float q[8];
        float run = 0.0f;
#pragma unroll
        for (int k = 0; k < 8; ++k) {
            const int m = (mv[k] == 255) ? 0 : mv[k];
            if (k < 4) w0 |= (unsigned int)m << (8 * k);
            else       w1 |= (unsigned int)m << (8 * (k - 4));
            run += (float)m;
            q[k] = run;                                // in-lane inclusive
        }

        // inclusive wave scan of lane totals
        float s = q[7];
#pragma unroll
        for (int off = 1; off < 64; off <<= 1) {
            const float n = __shfl_up(s, off, 64);
            if (lane >= off) s += n;
        }
        const float pre = s - q[7];                    // exclusive prefix
        float P[8];
#pragma unroll
        for (int k = 0; k < 8; ++k) P[k] = pre + q[k];
        const float total = __shfl(P[7], 63, 64);

        // window ends: P[i-16] at (lane-2, k); P[i+15] at (lane+1, 7) for
        // k==0 else (lane+2, k-1). Clamped lanes guarded by the i-tests.
        const int sl = (lane < 2) ? 0 : lane - 2;
        const int s1 = (lane > 62) ? 63 : lane + 1;
        const int s2 = (lane > 61) ? 63 : lane + 2;
        float plo[8], phi[8];
#pragma unroll
        for (int k = 0; k < 8; ++k) plo[k] = __shfl(P[k], sl, 64);
        phi[0] = __shfl(P[7], s1, 64);
#pragma unroll
        for (int k = 1; k < 8; ++k) phi[k] = __shfl(P[k - 1], s2, 64);

        unsigned int h0w = 0, h1w = 0;
#pragma unroll
        for (int k = 0; k < 8; ++k) {
            const int i = c0 + k;
            const float lo = (i >= PADR + 1) ? plo[k] : 0.0f;
            const float hi = (i + PADR <= Wn - 1) ? phi[k] : total;
            const unsigned int hv = (unsigned int)(hi - lo);   // exact, <=31
            if (k < 4) h0w |= hv << (8 * k);
            else       h1w |= hv << (8 * (k - 4));
        }
        h0w |= (w0 & 0x01010101u) << 7;                // mask bit in bit 7
        h1w |= (w1 & 0x01010101u) << 7;
        *reinterpret_cast<uint2*>(h8 + (size_t)r * Wn + c0) = make_uint2(h0w, h1w);
    }
}

// ---- pass B: vertical slide over combined u8 + loss math -----------------
// flat grid 1024; wave owns 2 rows; lane owns 8 cols. ALL global loads
// hoisted to the top so they sit in the VMEM queue while the 31-row
// packed-u16 window accumulates (latency hiding via MLP, not wave count).
__global__ void __launch_bounds__(256, 4)
fused_kernel(const float* __restrict__ pred,
             const unsigned char* __restrict__ hm8,
             float* __restrict__ part) {
    int b, bx;
    decode_fid(blockIdx.x, b, bx);
    const int t = threadIdx.x;
    const int lane = t & 63;
    const int wv = t >> 6;
    const int r0 = bx * 8 + wv * 2;
    const int c0 = lane * 8;

    const unsigned char* hb = hm8 + (size_t)b * Hn * Wn;
    const float* pb = pred + (size_t)b * 2 * Hn * Wn;
    const float* pb1 = pb + (size_t)Hn * Wn;

    // ---- hoisted loads: 8x float4 pred + 2x uint2 hm8 row words ----
    float4 qa00, qa01, qb00, qb01, qa10, qa11, qb10, qb11;
    uint2 mm0, mm1;
    qa00 = *reinterpret_cast<const float4*>(pb + (size_t)r0 * Wn + c0);
    qa01 = *reinterpret_cast<const float4*>(pb + (size_t)r0 * Wn + c0 + 4);
    qb00 = *reinterpret_cast<const float4*>(pb1 + (size_t)r0 * Wn + c0);
    qb01 = *reinterpret_cast<const float4*>(pb1 + (size_t)r0 * Wn + c0 + 4);
    qa10 = *reinterpret_cast<const float4*>(pb + (size_t)(r0 + 1) * Wn + c0);
    qa11 = *reinterpret_cast<const float4*>(pb + (size_t)(r0 + 1) * Wn + c0 + 4);
    qb10 = *reinterpret_cast<const float4*>(pb1 + (size_t)(r0 + 1) * Wn + c0);
    qb11 = *reinterpret_cast<const float4*>(pb1 + (size_t)(r0 + 1) * Wn + c0 + 4);
    mm0 = *reinterpret_cast<const uint2*>(hb + (size_t)r0 * Wn + c0);
    mm1 = *reinterpret_cast<const uint2*>(hb + (size_t)(r0 + 1) * Wn + c0);

    // ---- packed u16 vertical sums of hsum for row r0 (mask bit7 excluded) -
    unsigned int e0 = 0, o0 = 0, e1 = 0, o1 = 0;
    {
        const int glo = (r0 - PADR < 0) ? 0 : r0 - PADR;
        const int ghi = (r0 + PADR > Hn - 1) ? Hn - 1 : r0 + PADR;
        for (int g = glo; g <= ghi; ++g) {
            const uint2 x = *reinterpret_cast<const uint2*>(hb + (size_t)g * Wn + c0);
            e0 += x.x & 0x001F001Fu; o0 += (x.x >> 8) & 0x001F001Fu;
            e1 += x.y & 0x001F001Fu; o1 += (x.y >> 8) & 0x001F001Fu;
        }
    }

    float a_weit = 0.f, a_wbce = 0.f, a_inter = 0.f, a_card = 0.f;

#pragma unroll
    for (int rr = 0; rr < 2; ++rr) {
        const int r = r0 + rr;

        const float vs[8] = {
            (float)(e0 & 0xFFFFu), (float)(o0 & 0xFFFFu),
            (float)(e0 >> 16),     (float)(o0 >> 16),
            (float)(e1 & 0xFFFFu), (float)(o1 & 0xFFFFu),
            (float)(e1 >> 16),     (float)(o1 >> 16)};

        const uint2 mm = rr ? mm1 : mm0;
        const float pA[8] = {
            rr ? qa10.x : qa00.x, rr ? qa10.y : qa00.y,
            rr ? qa10.z : qa00.z, rr ? qa10.w : qa00.w,
            rr ? qa11.x : qa01.x, rr ? qa11.y : qa01.y,
            rr ? qa11.z : qa01.z, rr ? qa11.w : qa01.w};
        const float pB[8] = {
            rr ? qb10.x : qb00.x, rr ? qb10.y : qb00.y,
            rr ? qb10.z : qb00.z, rr ? qb10.w : qb00.w,
            rr ? qb11.x : qb01.x, rr ? qb11.y : qb01.y,
            rr ? qb11.z : qb01.z, rr ? qb11.w : qb01.w};

#pragma unroll
        for (int k = 0; k < 8; ++k) {
            const unsigned int mwrd = (k < 4) ? mm.x : mm.y;
            const int m = (mwrd >> (8 * (k & 3) + 7)) & 1;
            const float mf = (float)m;
            const float p0 = pA[k];
            const float p1 = pB[k];

            const float pooled = vs[k] * INV_KK;

            // lse = max + log(1 + exp(-|p0-p1|)): 1 exp + 1 log
            const float mx = fmaxf(p0, p1);
            const float lse = mx + __logf(1.0f + __expf(-fabsf(p0 - p1)));
            const float wbce = lse - (m ? p1 : p0);
            const float p1s = __expf(p1 - lse);

            const float weit = 1.0f + 5.0f * fabsf(pooled - mf);
            a_weit += weit;
            a_wbce += weit * wbce;
            a_inter += p1s * mf * weit;
            a_card += (p1s + mf) * weit;
        }

        if (rr == 0) {                                 // slide window 1 row
            const int ga = r + 1 + PADR;
            const int gs = r - PADR;
            if (ga < Hn) {
                const uint2 x = *reinterpret_cast<const uint2*>(hb + (size_t)ga * Wn + c0);
                e0 += x.x & 0x001F001Fu; o0 += (x.x >> 8) & 0x001F001Fu;
                e1 += x.y & 0x001F001Fu; o1 += (x.y >> 8) & 0x001F001Fu;
            }
            if (gs >= 0) {
                const uint2 x = *reinterpret_cast<const uint2*>(hb + (size_t)gs * Wn + c0);
                e0 -= x.x & 0x001F001Fu; o0 -= (x.x >> 8) & 0x001F001Fu;
                e1 -= x.y & 0x001F001Fu; o1 -= (x.y >> 8) & 0x001F001Fu;
            }
        }
    }

    // block reduction: 4 waves of 64
    __shared__ float red[4][4];
#pragma unroll
    for (int off = 32; off > 0; off >>= 1) {
        a_weit += __shfl_down(a_weit, off, 64);
        a_wbce += __shfl_down(a_wbce, off, 64);
        a_inter += __shfl_down(a_inter, off, 64);
        a_card += __shfl_down(a_card, off, 64);
    }
    if (lane == 0) {
        red[wv][0] = a_weit;
        red[wv][1] = a_wbce;
        red[wv][2] = a_inter;
        red[wv][3] = a_card;
    }
    __syncthreads();
    if (t < 4) {
        part[((size_t)b * 64 + bx) * 4 + t] =
            red[0][t] + red[1][t] + red[2][t] + red[3][t];
    }
}

// ------ single-block reduce of part[b][64][4] + per-batch loss + mean -----
__global__ void __launch_bounds__(1024)
reduce_finalize_kernel(const float* __restrict__ part, float* __restrict__ out) {
    const int t = threadIdx.x;
    const int b = t >> 6;
    const int l = t & 63;

    const float4 v = *reinterpret_cast<const float4*>(part + ((size_t)b * 64 + l) * 4);
    float a0 = v.x, a1 = v.y, a2 = v.z, a3 = v.w;
#pragma unroll
    for (int off = 32; off > 0; off >>= 1) {
        a0 += __shfl_down(a0, off, 64);
        a1 += __shfl_down(a1, off, 64);
        a2 += __shfl_down(a2, off, 64);
        a3 += __shfl_down(a3, off, 64);
    }

    __shared__ float loss[Bn];
    if (l == 0) {
        const float wbce = a1 / a0;
        const float uni = a3 - a2;                     // cardinality - inter
        const float wiou = 1.0f - (a2 + 1.0f) / (uni + 1.0f);
        loss[b] = wbce + wiou;
    }
    __syncthreads();
    if (t == 0) {
        float s = 0.0f;
#pragma unroll
        for (int k = 0; k < Bn; ++k) s += loss[k];
        out[0] = s * (1.0f / (float)Bn);
    }
}

extern "C" void kernel_launch(void* const* d_in, const int* in_sizes, int n_in,
                              void* d_out, int out_size, void* d_ws, size_t ws_size,
                              hipStream_t stream) {
    const float* pred = (const float*)d_in[0];
    const int* mask = (const int*)d_in[1];
    unsigned char* hm8 = (unsigned char*)d_ws;                   // 4 MB
    float* part = (float*)(hm8 + (size_t)Bn * Hn * Wn);          // 16 KB
    float* out = (float*)d_out;

    hipLaunchKernelGGL(pack_hbox_kernel, dim3(NBLK), dim3(256), 0, stream,
                       mask, hm8);
    hipLaunchKernelGGL(fused_kernel, dim3(NBLK), dim3(256), 0, stream,
                       pred, hm8, part);
    hipLaunchKernelGGL(reduce_finalize_kernel, dim3(1), dim3(1024), 0, stream,
                       part, out);
}

// Round 12
// 23.445 us; speedup vs baseline: 1.1785x; 1.1785x over previous
//
#include <hip/hip_runtime.h>

// Problem constants (from reference setup_inputs)
constexpr int Bn = 16;
constexpr int Hn = 512;
constexpr int Wn = 512;
constexpr int PADR = 15;              // 31x31 window, pad 15
constexpr float INV_KK = 1.0f / (31.0f * 31.0f);
constexpr int NBLK = 1024;            // 64 row-groups x 16 batches
constexpr int HALO = 38;              // 8 output rows + 15 above + 15 below

// XCD-aware flat-block decode: blocks with equal (fid%8) land on the same
// XCD (dispatch round-robins). Pin batches {2x,2x+1} to XCD x so the u8
// buffer (256 KB/batch) stays L2-resident. Bijective for grids 16*G.
__device__ __forceinline__ void decode_fid(int fid, int& b, int& grp) {
    b = (fid & 7) * 2 + ((fid >> 3) & 1);
    grp = fid >> 4;
}

// ---- pass A: pack mask + horizontal 31-tap box -> combined u8 ------------
// byte = hbox(m)[0..31] | (m << 7).
// flat grid 1024; 4 waves; wave owns 2 rows; lane owns 8 cols.
__global__ void pack_hbox_kernel(const int* __restrict__ mask,
                                 unsigned char* __restrict__ hm8) {
    int b, grp;
    decode_fid(blockIdx.x, b, grp);
    const int lane = threadIdx.x & 63;
    const int wv = threadIdx.x >> 6;
    const int c0 = lane * 8;

    const int* mb = mask + (size_t)b * Hn * Wn;
    unsigned char* h8 = hm8 + (size_t)b * Hn * Wn;

#pragma unroll
    for (int rr = 0; rr < 2; ++rr) {
        const int r = grp * 8 + wv * 2 + rr;
        const int4 a = *reinterpret_cast<const int4*>(mb + (size_t)r * Wn + c0);
        const int4 c = *reinterpret_cast<const int4*>(mb + (size_t)r * Wn + c0 + 4);
        const int mv[8] = {a.x, a.y, a.z, a.w, c.x, c.y, c.z, c.w};

        unsigned int w0 = 0, w1 = 0;                   // packed mask bytes
        float q[8];
        float run = 0.0f;
#pragma unroll
        for (int k = 0; k < 8; ++k) {
            const int m = (mv[k] == 255) ? 0 : mv[k];
            if (k < 4) w0 |= (unsigned int)m << (8 * k);
            else       w1 |= (unsigned int)m << (8 * (k - 4));
            run += (float)m;
            q[k] = run;                                // in-lane inclusive
        }

        // inclusive wave scan of lane totals
        float s = q[7];
#pragma unroll
        for (int off = 1; off < 64; off <<= 1) {
            const float n = __shfl_up(s, off, 64);
            if (lane >= off) s += n;
        }
        const float pre = s - q[7];                    // exclusive prefix
        float P[8];
#pragma unroll
        for (int k = 0; k < 8; ++k) P[k] = pre + q[k];
        const float total = __shfl(P[7], 63, 64);

        // window ends: P[i-16] at (lane-2, k); P[i+15] at (lane+1, 7) for
        // k==0 else (lane+2, k-1). Clamped lanes guarded by the i-tests.
        const int sl = (lane < 2) ? 0 : lane - 2;
        const int s1 = (lane > 62) ? 63 : lane + 1;
        const int s2 = (lane > 61) ? 63 : lane + 2;
        float plo[8], phi[8];
#pragma unroll
        for (int k = 0; k < 8; ++k) plo[k] = __shfl(P[k], sl, 64);
        phi[0] = __shfl(P[7], s1, 64);
#pragma unroll
        for (int k = 1; k < 8; ++k) phi[k] = __shfl(P[k - 1], s2, 64);

        unsigned int h0w = 0, h1w = 0;
#pragma unroll
        for (int k = 0; k < 8; ++k) {
            const int i = c0 + k;
            const float lo = (i >= PADR + 1) ? plo[k] : 0.0f;
            const float hi = (i + PADR <= Wn - 1) ? phi[k] : total;
            const unsigned int hv = (unsigned int)(hi - lo);   // exact, <=31
            if (k < 4) h0w |= hv << (8 * k);
            else       h1w |= hv << (8 * (k - 4));
        }
        h0w |= (w0 & 0x01010101u) << 7;                // mask bit in bit 7
        h1w |= (w1 & 0x01010101u) << 7;
        *reinterpret_cast<uint2*>(h8 + (size_t)r * Wn + c0) = make_uint2(h0w, h1w);
    }
}

// ---- pass B: LDS-staged vertical slide over combined u8 + loss math ------
// flat grid 1024; block owns 8 output rows and stages its 38 hm8 rows
// (19 KB) into LDS once (coalesced uint4), then each wave's 31-row window
// runs on ds_read_b64 instead of 33 L2 round-trips per wave.
__global__ void fused_kernel(const float* __restrict__ pred,
                             const unsigned char* __restrict__ hm8,
                             float* __restrict__ part) {
    int b, bx;
    decode_fid(blockIdx.x, b, bx);
    const int t = threadIdx.x;
    const int lane = t & 63;
    const int wv = t >> 6;
    const int h0 = bx * 8;                             // first output row
    const int rlo = h0 - PADR;                         // halo start (may be <0)
    const int r0 = h0 + wv * 2;                        // this wave's first row
    const int c0 = lane * 8;

    const unsigned char* hb = hm8 + (size_t)b * Hn * Wn;
    const float* pb = pred + (size_t)b * 2 * Hn * Wn;
    const float* pb1 = pb + (size_t)Hn * Wn;

    __shared__ unsigned char hs[HALO * Wn];            // 19456 B
    __shared__ float red[4][4];

    // ---- cooperative stage: 38 rows x 32 uint4-chunks, zero-fill halo ----
    for (int idx = t; idx < HALO * (Wn / 16); idx += 256) {
        const int row = idx >> 5;                      // 0..37
        const int ch = idx & 31;                       // 16B chunk in row
        const int g = rlo + row;
        uint4 v = make_uint4(0u, 0u, 0u, 0u);
        if (g >= 0 && g < Hn)
            v = *reinterpret_cast<const uint4*>(hb + (size_t)g * Wn + ch * 16);
        *reinterpret_cast<uint4*>(&hs[row * Wn + ch * 16]) = v;
    }
    __syncthreads();

    // ---- packed u16 vertical sums from LDS (mask bit7 excluded) ----
    // LDS row of global row g is (g - rlo); window rows for r0 are
    // LDS rows wv*2 .. wv*2+30; zero-filled rows add 0 (no bounds checks).
    const int base = wv * 2;
    unsigned int e0 = 0, o0 = 0, e1 = 0, o1 = 0;
    for (int j = 0; j < 31; ++j) {
        const uint2 x = *reinterpret_cast<const uint2*>(&hs[(base + j) * Wn + c0]);
        e0 += x.x & 0x001F001Fu; o0 += (x.x >> 8) & 0x001F001Fu;
        e1 += x.y & 0x001F001Fu; o1 += (x.y >> 8) & 0x001F001Fu;
    }

    float a_weit = 0.f, a_wbce = 0.f, a_inter = 0.f, a_card = 0.f;

#pragma unroll
    for (int rr = 0; rr < 2; ++rr) {
        const int r = r0 + rr;

        const float vs[8] = {
            (float)(e0 & 0xFFFFu), (float)(o0 & 0xFFFFu),
            (float)(e0 >> 16),     (float)(o0 >> 16),
            (float)(e1 & 0xFFFFu), (float)(o1 & 0xFFFFu),
            (float)(e1 >> 16),     (float)(o1 >> 16)};

        // mask bits from the staged combined byte (LDS row base+15+rr)
        const uint2 mm = *reinterpret_cast<const uint2*>(
            &hs[(base + PADR + rr) * Wn + c0]);
        const float4 qa0 = *reinterpret_cast<const float4*>(pb + (size_t)r * Wn + c0);
        const float4 qa1 = *reinterpret_cast<const float4*>(pb + (size_t)r * Wn + c0 + 4);
        const float4 qb0 = *reinterpret_cast<const float4*>(pb1 + (size_t)r * Wn + c0);
        const float4 qb1 = *reinterpret_cast<const float4*>(pb1 + (size_t)r * Wn + c0 + 4);
        const float pA[8] = {qa0.x, qa0.y, qa0.z, qa0.w, qa1.x, qa1.y, qa1.z, qa1.w};
        const float pB[8] = {qb0.x, qb0.y, qb0.z, qb0.w, qb1.x, qb1.y, qb1.z, qb1.w};

#pragma unroll
        for (int k = 0; k < 8; ++k) {
            const unsigned int mwrd = (k < 4) ? mm.x : mm.y;
            const int m = (mwrd >> (8 * (k & 3) + 7)) & 1;
            const float mf = (float)m;
            const float p0 = pA[k];
            const float p1 = pB[k];

            const float pooled = vs[k] * INV_KK;

            // lse = max + log(1 + exp(-|p0-p1|)): 1 exp + 1 log
            const float mx = fmaxf(p0, p1);
            const float lse = mx + __logf(1.0f + __expf(-fabsf(p0 - p1)));
            const float wbce = lse - (m ? p1 : p0);
            const float p1s = __expf(p1 - lse);

            const float weit = 1.0f + 5.0f * fabsf(pooled - mf);
            a_weit += weit;
            a_wbce += weit * wbce;
            a_inter += p1s * mf * weit;
            a_card += (p1s + mf) * weit;
        }

        if (rr == 0) {                                 // slide window 1 row
            // add LDS row base+31 (global r0+16), sub base+0 (global r0-15);
            // zero-filled rows make this correct without bounds checks.
            const uint2 xa = *reinterpret_cast<const uint2*>(
                &hs[(base + 31) * Wn + c0]);
            e0 += xa.x & 0x001F001Fu; o0 += (xa.x >> 8) & 0x001F001Fu;
            e1 += xa.y & 0x001F001Fu; o1 += (xa.y >> 8) & 0x001F001Fu;
            const uint2 xs = *reinterpret_cast<const uint2*>(
                &hs[(base + 0) * Wn + c0]);
            e0 -= xs.x & 0x001F001Fu; o0 -= (xs.x >> 8) & 0x001F001Fu;
            e1 -= xs.y & 0x001F001Fu; o1 -= (xs.y >> 8) & 0x001F001Fu;
        }
    }

    // block reduction: 4 waves of 64
#pragma unroll
    for (int off = 32; off > 0; off >>= 1) {
        a_weit += __shfl_down(a_weit, off, 64);
        a_wbce += __shfl_down(a_wbce, off, 64);
        a_inter += __shfl_down(a_inter, off, 64);
        a_card += __shfl_down(a_card, off, 64);
    }
    if (lane == 0) {
        red[wv][0] = a_weit;
        red[wv][1] = a_wbce;
        red[wv][2] = a_inter;
        red[wv][3] = a_card;
    }
    __syncthreads();
    if (t < 4) {
        part[((size_t)b * 64 + bx) * 4 + t] =
            red[0][t] + red[1][t] + red[2][t] + red[3][t];
    }
}

// ------ single-block reduce of part[b][64][4] + per-batch loss + mean -----
__global__ void __launch_bounds__(1024)
reduce_finalize_kernel(const float* __restrict__ part, float* __restrict__ out) {
    const int t = threadIdx.x;
    const int b = t >> 6;
    const int l = t & 63;

    const float4 v = *reinterpret_cast<const float4*>(part + ((size_t)b * 64 + l) * 4);
    float a0 = v.x, a1 = v.y, a2 = v.z, a3 = v.w;
#pragma unroll
    for (int off = 32; off > 0; off >>= 1) {
        a0 += __shfl_down(a0, off, 64);
        a1 += __shfl_down(a1, off, 64);
        a2 += __shfl_down(a2, off, 64);
        a3 += __shfl_down(a3, off, 64);
    }

    __shared__ float loss[Bn];
    if (l == 0) {
        const float wbce = a1 / a0;
        const float uni = a3 - a2;                     // cardinality - inter
        const float wiou = 1.0f - (a2 + 1.0f) / (uni + 1.0f);
        loss[b] = wbce + wiou;
    }
    __syncthreads();
    if (t == 0) {
        float s = 0.0f;
#pragma unroll
        for (int k = 0; k < Bn; ++k) s += loss[k];
        out[0] = s * (1.0f / (float)Bn);
    }
}

extern "C" void kernel_launch(void* const* d_in, const int* in_sizes, int n_in,
                              void* d_out, int out_size, void* d_ws, size_t ws_size,
                              hipStream_t stream) {
    const float* pred = (const float*)d_in[0];
    const int* mask = (const int*)d_in[1];
    unsigned char* hm8 = (unsigned char*)d_ws;                   // 4 MB
    float* part = (float*)(hm8 + (size_t)Bn * Hn * Wn);          // 16 KB
    float* out = (float*)d_out;

    hipLaunchKernelGGL(pack_hbox_kernel, dim3(NBLK), dim3(256), 0, stream,
                       mask, hm8);
    hipLaunchKernelGGL(fused_kernel, dim3(NBLK), dim3(256), 0, stream,
                       pred, hm8, part);
    hipLaunchKernelGGL(reduce_finalize_kernel, dim3(1), dim3(1024), 0, stream,
                       part, out);
}

// Round 13
// 23.222 us; speedup vs baseline: 1.1898x; 1.0096x over previous
//
#include <hip/hip_runtime.h>

// Problem constants (from reference setup_inputs)
constexpr int Bn = 16;
constexpr int Hn = 512;
constexpr int Wn = 512;
constexpr int PADR = 15;              // 31x31 window, pad 15
constexpr float INV_KK = 1.0f / (31.0f * 31.0f);
constexpr int NBLK = 1024;            // 64 row-groups x 16 batches
constexpr int HALO = 38;              // 8 output rows + 15 above + 15 below

// XCD-aware flat-block decode: blocks with equal (fid%8) land on the same
// XCD (dispatch round-robins). Pin batches {2x,2x+1} to XCD x so the u8
// buffer (256 KB/batch) stays L2-resident. Bijective for grids 16*G.
__device__ __forceinline__ void decode_fid(int fid, int& b, int& grp) {
    b = (fid & 7) * 2 + ((fid >> 3) & 1);
    grp = fid >> 4;
}

// ---- pass A: pack mask + horizontal 31-tap box -> combined u8 ------------
// byte = hbox(m)[0..31] | (m << 7).
// flat grid 1024; 4 waves; wave owns 2 rows; lane owns 8 cols.
__global__ void pack_hbox_kernel(const int* __restrict__ mask,
                                 unsigned char* __restrict__ hm8) {
    int b, grp;
    decode_fid(blockIdx.x, b, grp);
    const int lane = threadIdx.x & 63;
    const int wv = threadIdx.x >> 6;
    const int c0 = lane * 8;

    const int* mb = mask + (size_t)b * Hn * Wn;
    unsigned char* h8 = hm8 + (size_t)b * Hn * Wn;

#pragma unroll
    for (int rr = 0; rr < 2; ++rr) {
        const int r = grp * 8 + wv * 2 + rr;
        const int4 a = *reinterpret_cast<const int4*>(mb + (size_t)r * Wn + c0);
        const int4 c = *reinterpret_cast<const int4*>(mb + (size_t)r * Wn + c0 + 4);
        const int mv[8] = {a.x, a.y, a.z, a.w, c.x, c.y, c.z, c.w};

        unsigned int w0 = 0, w1 = 0;                   // packed mask bytes
        float q[8];
        float run = 0.0f;
#pragma unroll
        for (int k = 0; k < 8; ++k) {
            const int m = (mv[k] == 255) ? 0 : mv[k];
            if (k < 4) w0 |= (unsigned int)m << (8 * k);
            else       w1 |= (unsigned int)m << (8 * (k - 4));
            run += (float)m;
            q[k] = run;                                // in-lane inclusive
        }

        // inclusive wave scan of lane totals
        float s = q[7];
#pragma unroll
        for (int off = 1; off < 64; off <<= 1) {
            const float n = __shfl_up(s, off, 64);
            if (lane >= off) s += n;
        }
        const float pre = s - q[7];                    // exclusive prefix
        float P[8];
#pragma unroll
        for (int k = 0; k < 8; ++k) P[k] = pre + q[k];
        const float total = __shfl(P[7], 63, 64);

        // window ends: P[i-16] at (lane-2, k); P[i+15] at (lane+1, 7) for
        // k==0 else (lane+2, k-1). Clamped lanes guarded by the i-tests.
        const int sl = (lane < 2) ? 0 : lane - 2;
        const int s1 = (lane > 62) ? 63 : lane + 1;
        const int s2 = (lane > 61) ? 63 : lane + 2;
        float plo[8], phi[8];
#pragma unroll
        for (int k = 0; k < 8; ++k) plo[k] = __shfl(P[k], sl, 64);
        phi[0] = __shfl(P[7], s1, 64);
#pragma unroll
        for (int k = 1; k < 8; ++k) phi[k] = __shfl(P[k - 1], s2, 64);

        unsigned int h0w = 0, h1w = 0;
#pragma unroll
        for (int k = 0; k < 8; ++k) {
            const int i = c0 + k;
            const float lo = (i >= PADR + 1) ? plo[k] : 0.0f;
            const float hi = (i + PADR <= Wn - 1) ? phi[k] : total;
            const unsigned int hv = (unsigned int)(hi - lo);   // exact, <=31
            if (k < 4) h0w |= hv << (8 * k);
            else       h1w |= hv << (8 * (k - 4));
        }
        h0w |= (w0 & 0x01010101u) << 7;                // mask bit in bit 7
        h1w |= (w1 & 0x01010101u) << 7;
        *reinterpret_cast<uint2*>(h8 + (size_t)r * Wn + c0) = make_uint2(h0w, h1w);
    }
}

// ---- pass B: LDS-staged vertical slide over combined u8 + loss math ------
// flat grid 1024; block stages its 38 hm8 rows (19 KB) into LDS once, then
// each wave's 31-row window runs on LDS. Window init uses two-tier SWAR:
// u8 groups of <=8 rows (bit7 masked; 8*31=248<256, no overflow), then one
// u16 unpack per group -- ~1/3 the VALU of per-row u16 unpacking.
__global__ void fused_kernel(const float* __restrict__ pred,
                             const unsigned char* __restrict__ hm8,
                             float* __restrict__ part) {
    int b, bx;
    decode_fid(blockIdx.x, b, bx);
    const int t = threadIdx.x;
    const int lane = t & 63;
    const int wv = t >> 6;
    const int h0 = bx * 8;                             // first output row
    const int rlo = h0 - PADR;                         // halo start (may be <0)
    const int r0 = h0 + wv * 2;                        // this wave's first row
    const int c0 = lane * 8;

    const unsigned char* hb = hm8 + (size_t)b * Hn * Wn;
    const float* pb = pred + (size_t)b * 2 * Hn * Wn;
    const float* pb1 = pb + (size_t)Hn * Wn;

    __shared__ unsigned char hs[HALO * Wn];            // 19456 B
    __shared__ float red[4][4];

    // ---- cooperative stage: 38 rows x 32 uint4-chunks, zero-fill halo ----
    for (int idx = t; idx < HALO * (Wn / 16); idx += 256) {
        const int row = idx >> 5;                      // 0..37
        const int ch = idx & 31;                       // 16B chunk in row
        const int g = rlo + row;
        uint4 v = make_uint4(0u, 0u, 0u, 0u);
        if (g >= 0 && g < Hn)
            v = *reinterpret_cast<const uint4*>(hb + (size_t)g * Wn + ch * 16);
        *reinterpret_cast<uint4*>(&hs[row * Wn + ch * 16]) = v;
    }
    __syncthreads();

    // ---- packed vertical sums from LDS: u8 groups -> u16 totals ----
    const int base = wv * 2;
    unsigned int e0 = 0, o0 = 0, e1 = 0, o1 = 0;
#pragma unroll
    for (int g4 = 0; g4 < 4; ++g4) {
        const int j0 = g4 * 8;
        const int jn = (g4 == 3) ? 7 : 8;              // rows 0..30
        unsigned int gx = 0, gy = 0;
#pragma unroll
        for (int j = 0; j < 8; ++j) {
            if (j < jn) {
                const uint2 x = *reinterpret_cast<const uint2*>(
                    &hs[(base + j0 + j) * Wn + c0]);
                gx += x.x & 0x7F7F7F7Fu;               // strip mask bit7
                gy += x.y & 0x7F7F7F7Fu;
            }
        }
        e0 += gx & 0x00FF00FFu; o0 += (gx >> 8) & 0x00FF00FFu;
        e1 += gy & 0x00FF00FFu; o1 += (gy >> 8) & 0x00FF00FFu;
    }

    float a_weit = 0.f, a_wbce = 0.f, a_inter = 0.f, a_card = 0.f;

#pragma unroll
    for (int rr = 0; rr < 2; ++rr) {
        const int r = r0 + rr;

        const float vs[8] = {
            (float)(e0 & 0xFFFFu), (float)(o0 & 0xFFFFu),
            (float)(e0 >> 16),     (float)(o0 >> 16),
            (float)(e1 & 0xFFFFu), (float)(o1 & 0xFFFFu),
            (float)(e1 >> 16),     (float)(o1 >> 16)};

        // mask bits from the staged combined byte (LDS row base+15+rr)
        const uint2 mm = *reinterpret_cast<const uint2*>(
            &hs[(base + PADR + rr) * Wn + c0]);
        const float4 qa0 = *reinterpret_cast<const float4*>(pb + (size_t)r * Wn + c0);
        const float4 qa1 = *reinterpret_cast<const float4*>(pb + (size_t)r * Wn + c0 + 4);
        const float4 qb0 = *reinterpret_cast<const float4*>(pb1 + (size_t)r * Wn + c0);
        const float4 qb1 = *reinterpret_cast<const float4*>(pb1 + (size_t)r * Wn + c0 + 4);
        const float pA[8] = {qa0.x, qa0.y, qa0.z, qa0.w, qa1.x, qa1.y, qa1.z, qa1.w};
        const float pB[8] = {qb0.x, qb0.y, qb0.z, qb0.w, qb1.x, qb1.y, qb1.z, qb1.w};

#pragma unroll
        for (int k = 0; k < 8; ++k) {
            const unsigned int mwrd = (k < 4) ? mm.x : mm.y;
            const int m = (mwrd >> (8 * (k & 3) + 7)) & 1;
            const float mf = (float)m;
            const float p0 = pA[k];
            const float p1 = pB[k];

            const float pooled = vs[k] * INV_KK;

            // softmax pieces: e = exp(-|d|); log path and rcp path are
            // independent (no exp->log->exp chain).
            const float mx = fmaxf(p0, p1);
            const float e = __expf(-fabsf(p0 - p1));
            const float one_e = 1.0f + e;
            const float lse = mx + __logf(one_e);
            const float wbce = lse - (m ? p1 : p0);
            const float inv = __builtin_amdgcn_rcpf(one_e);
            const float p1s = (p1 >= p0) ? inv : e * inv;   // sigmoid(p1-p0)

            const float weit = 1.0f + 5.0f * fabsf(pooled - mf);
            a_weit += weit;
            a_wbce += weit * wbce;
            a_inter += p1s * mf * weit;
            a_card += (p1s + mf) * weit;
        }

        if (rr == 0) {                                 // slide window 1 row
            // add LDS row base+31 (global r0+16), sub base+0 (global r0-15);
            // zero-filled halo rows make this correct without bounds checks.
            const uint2 xa = *reinterpret_cast<const uint2*>(
                &hs[(base + 31) * Wn + c0]);
            e0 += xa.x & 0x007F007Fu; o0 += (xa.x >> 8) & 0x007F007Fu;
            e1 += xa.y & 0x007F007Fu; o1 += (xa.y >> 8) & 0x007F007Fu;
            const uint2 xs = *reinterpret_cast<const uint2*>(
                &hs[(base + 0) * Wn + c0]);
            e0 -= xs.x & 0x007F007Fu; o0 -= (xs.x >> 8) & 0x007F007Fu;
            e1 -= xs.y & 0x007F007Fu; o1 -= (xs.y >> 8) & 0x007F007Fu;
        }
    }

    // block reduction: 4 waves of 64
#pragma unroll
    for (int off = 32; off > 0; off >>= 1) {
        a_weit += __shfl_down(a_weit, off, 64);
        a_wbce += __shfl_down(a_wbce, off, 64);
        a_inter += __shfl_down(a_inter, off, 64);
        a_card += __shfl_down(a_card, off, 64);
    }
    if (lane == 0) {
        red[wv][0] = a_weit;
        red[wv][1] = a_wbce;
        red[wv][2] = a_inter;
        red[wv][3] = a_card;
    }
    __syncthreads();
    if (t < 4) {
        part[((size_t)b * 64 + bx) * 4 + t] =
            red[0][t] + red[1][t] + red[2][t] + red[3][t];
    }
}

// ------ single-block reduce of part[b][64][4] + per-batch loss + mean -----
__global__ void __launch_bounds__(1024)
reduce_finalize_kernel(const float* __restrict__ part, float* __restrict__ out) {
    const int t = threadIdx.x;
    const int b = t >> 6;
    const int l = t & 63;

    const float4 v = *reinterpret_cast<const float4*>(part + ((size_t)b * 64 + l) * 4);
    float a0 = v.x, a1 = v.y, a2 = v.z, a3 = v.w;
#pragma unroll
    for (int off = 32; off > 0; off >>= 1) {
        a0 += __shfl_down(a0, off, 64);
        a1 += __shfl_down(a1, off, 64);
        a2 += __shfl_down(a2, off, 64);
        a3 += __shfl_down(a3, off, 64);
    }

    __shared__ float loss[Bn];
    if (l == 0) {
        const float wbce = a1 / a0;
        const float uni = a3 - a2;                     // cardinality - inter
        const float wiou = 1.0f - (a2 + 1.0f) / (uni + 1.0f);
        loss[b] = wbce + wiou;
    }
    __syncthreads();
    if (t == 0) {
        float s = 0.0f;
#pragma unroll
        for (int k = 0; k < Bn; ++k) s += loss[k];
        out[0] = s * (1.0f / (float)Bn);
    }
}

extern "C" void kernel_launch(void* const* d_in, const int* in_sizes, int n_in,
                              void* d_out, int out_size, void* d_ws, size_t ws_size,
                              hipStream_t stream) {
    const float* pred = (const float*)d_in[0];
    const int* mask = (const int*)d_in[1];
    unsigned char* hm8 = (unsigned char*)d_ws;                   // 4 MB
    float* part = (float*)(hm8 + (size_t)Bn * Hn * Wn);          // 16 KB
    float* out = (float*)d_out;

    hipLaunchKernelGGL(pack_hbox_kernel, dim3(NBLK), dim3(256), 0, stream,
                       mask, hm8);
    hipLaunchKernelGGL(fused_kernel, dim3(NBLK), dim3(256), 0, stream,
                       pred, hm8, part);
    hipLaunchKernelGGL(reduce_finalize_kernel, dim3(1), dim3(1024), 0, stream,
                       part, out);
}